// Round 11
// baseline (523.017 us; speedup 1.0000x reference)
//
#include <hip/hip_runtime.h>
#include <math.h>

#define D 128

typedef __attribute__((ext_vector_type(8))) short short8v;     // raw 16-bit x8
typedef __attribute__((ext_vector_type(4))) float f32x4;       // MFMA acc
typedef _Float16 half2n __attribute__((ext_vector_type(2)));   // packed f16 pair
typedef _Float16 half8v __attribute__((ext_vector_type(8)));   // MFMA f16 frag

__device__ inline short f2h(float f) {                         // f32 -> f16 (RNE)
    _Float16 h = (_Float16)f;
    return __builtin_bit_cast(short, h);
}
__device__ inline float h2f(short s) {
    return (float)__builtin_bit_cast(_Float16, s);
}
// e5m2 = top byte of f16, RNE round on bit 8.
__device__ inline unsigned char h2e5(short hs) {
    unsigned u = (unsigned short)hs;
    u = u + 0x7Fu + ((u >> 8) & 1u);
    return (unsigned char)(u >> 8);
}
__device__ inline half2n u2h2(unsigned u) { return __builtin_bit_cast(half2n, u); }
__device__ inline unsigned h22u(half2n h) { return __builtin_bit_cast(unsigned, h); }

// Fast tanh: one v_exp_f32 + rcp; branch-free, exact at 0/inf.
__device__ inline float fast_tanh(float x) {
    float a = fabsf(x);
    float e = __expf(-2.0f * a);
    float t = (1.0f - e) / (1.0f + e);
    return copysignf(t, x);
}

// e5m2 x-row (8 bytes, order [e2,e0,e3,e1][e6,e4,e7,e5]) x f16 rel pairs -> 4 half2 accs.
__device__ inline void e5fma(uint2 xw, uint4 rw,
                             half2n& a0, half2n& a1, half2n& a2, half2n& a3) {
    a0 += u2h2(xw.x & 0xFF00FF00u) * u2h2(rw.x);          // (e0,e1)
    a1 += u2h2((xw.x << 8) & 0xFF00FF00u) * u2h2(rw.y);   // (e2,e3)
    a2 += u2h2(xw.y & 0xFF00FF00u) * u2h2(rw.z);          // (e4,e5)
    a3 += u2h2((xw.y << 8) & 0xFF00FF00u) * u2h2(rw.w);   // (e6,e7)
}
// f16 x-row x scalar-splat weight -> 4 half2 accs.
__device__ inline void h16fma(uint4 xw, half2n w2,
                              half2n& a0, half2n& a1, half2n& a2, half2n& a3) {
    a0 += u2h2(xw.x) * w2;
    a1 += u2h2(xw.y) * w2;
    a2 += u2h2(xw.z) * w2;
    a3 += u2h2(xw.w) * w2;
}
__device__ inline half2n red2(half2n a) {
    a += u2h2((unsigned)__shfl_xor(__builtin_bit_cast(int, a), 16));
    a += u2h2((unsigned)__shfl_xor(__builtin_bit_cast(int, a), 32));
    return a;
}

// ===========================================================================
// Concatenated CSR build (unchanged).
// ===========================================================================
__global__ void hist_both(const int* __restrict__ dst_e,
                          const int* __restrict__ dst_j,
                          int* __restrict__ cnt, int E, int EJ, int N) {
    int i = blockIdx.x * blockDim.x + threadIdx.x;
    if (i < E) atomicAdd(&cnt[dst_e[i]], 1);
    else if (i < E + EJ) atomicAdd(&cnt[N + dst_j[i - E]], 1);
}

__global__ void scan1(const int* __restrict__ cnt, int* __restrict__ offs,
                      int* __restrict__ bsum, int M) {
    __shared__ int sh[256];
    int t = threadIdx.x;
    int base = blockIdx.x * 1024 + t * 4;
    int v0 = 0, v1 = 0, v2 = 0, v3 = 0;
    if (base + 0 < M) v0 = cnt[base + 0];
    if (base + 1 < M) v1 = cnt[base + 1];
    if (base + 2 < M) v2 = cnt[base + 2];
    if (base + 3 < M) v3 = cnt[base + 3];
    int tsum = v0 + v1 + v2 + v3;
    sh[t] = tsum;
    __syncthreads();
    for (int off = 1; off < 256; off <<= 1) {
        int x = (t >= off) ? sh[t - off] : 0;
        __syncthreads();
        sh[t] += x;
        __syncthreads();
    }
    int excl = sh[t] - tsum;
    if (base + 0 < M) offs[base + 0] = excl;
    excl += v0;
    if (base + 1 < M) offs[base + 1] = excl;
    excl += v1;
    if (base + 2 < M) offs[base + 2] = excl;
    excl += v2;
    if (base + 3 < M) offs[base + 3] = excl;
    if (t == 255) bsum[blockIdx.x] = sh[255];
}

__global__ void scan2(int* __restrict__ bsum, int NB) {
    __shared__ int sh[256];
    int t = threadIdx.x;
    int v = (t < NB) ? bsum[t] : 0;
    sh[t] = v;
    __syncthreads();
    for (int off = 1; off < 256; off <<= 1) {
        int x = (t >= off) ? sh[t - off] : 0;
        __syncthreads();
        sh[t] += x;
        __syncthreads();
    }
    if (t < NB) bsum[t] = sh[t] - v;
}

__global__ void scan3(int* __restrict__ offs, const int* __restrict__ bsum,
                      int* __restrict__ cur, int M) {
    int i = blockIdx.x * blockDim.x + threadIdx.x;
    if (i < M) {
        int o = offs[i] + bsum[i >> 10];
        offs[i] = o;
        cur[i] = o;
    }
}

__global__ void fill_both(const int* __restrict__ src_e,
                          const int* __restrict__ dst_e,
                          const int* __restrict__ et,
                          const int* __restrict__ src_j,
                          const int* __restrict__ dst_j,
                          const float* __restrict__ ew,
                          int* __restrict__ cur, int2* __restrict__ pairs,
                          int E, int EJ, int N) {
    int i = blockIdx.x * blockDim.x + threadIdx.x;
    if (i < E) {
        int p = atomicAdd(&cur[dst_e[i]], 1);
        pairs[p] = make_int2(src_e[i], et[i]);
    } else if (i < E + EJ) {
        int e = i - E;
        int p = atomicAdd(&cur[N + dst_j[e]], 1);
        pairs[p] = make_int2(src_j[e], __float_as_int(ew[e]));
    }
}

// ===========================================================================
// Weight pack (f16), stacked K: rows 0..127 = W, 128..255 = Wl.
// ===========================================================================
__global__ void pack_w(const float* __restrict__ W1, const float* __restrict__ Wl1,
                       const float* __restrict__ W2, const float* __restrict__ Wl2,
                       short* __restrict__ B1, short* __restrict__ B2) {
    int lane = threadIdx.x;          // 64
    int tile = blockIdx.x & 63;
    const float* W  = (blockIdx.x < 64) ? W1 : W2;
    const float* Wl = (blockIdx.x < 64) ? Wl1 : Wl2;
    short* Bpk      = (blockIdx.x < 64) ? B1 : B2;
    int tn = tile >> 3, tk = tile & 7;
    int n = tn * 16 + (lane & 15);
    int k0 = tk * 32 + (lane >> 4) * 8;
    short* o = Bpk + ((size_t)tile * 64 + lane) * 8;
#pragma unroll
    for (int j = 0; j < 8; j++) {
        int k = k0 + j;
        float f = (k < D) ? W[(size_t)k * D + n] : Wl[(size_t)(k - D) * D + n];
        o[j] = f2h(f);
    }
}

// rel_emb fp32 -> f16, both layers; plus one zero row at index R each.
__global__ void cvt_rel(const float* __restrict__ r1, const float* __restrict__ r2,
                        short* __restrict__ o1, short* __restrict__ o2, int RD) {
    int i = blockIdx.x * blockDim.x + threadIdx.x;   // one thread per 4 elems
    int half = RD >> 2;
    if (i < 2 * half) {
        const float* src = (i < half) ? r1 : r2;
        short* dst = (i < half) ? o1 : o2;
        int j = (i < half) ? i : i - half;
        float4 v = *(const float4*)(src + (size_t)j * 4);
        short4 o;
        o.x = f2h(v.x); o.y = f2h(v.y); o.z = f2h(v.z); o.w = f2h(v.w);
        *(short4*)(dst + (size_t)j * 4) = o;
    } else {
        int extra = i - 2 * half;
        if (extra < 64) {
            short* dst = (extra < 32) ? o1 : o2;
            int j = extra & 31;
            short4 z; z.x = 0; z.y = 0; z.z = 0; z.w = 0;
            *(short4*)(dst + (size_t)RD + j * 4) = z;
        }
    }
}

// emb -> Abf1 x-half (f16) + X8_1 (e5m2, byte order [e2,e0,e3,e1]); change -> out.
__global__ void cvt_emb_copy(const float* __restrict__ emb,
                             const float* __restrict__ change,
                             short* __restrict__ Abf,
                             unsigned char* __restrict__ X8,
                             float* __restrict__ out, int N) {
    int i = blockIdx.x * blockDim.x + threadIdx.x;   // one thread per 4 elems
    int row = i >> 5;
    int c4 = (i & 31) * 4;
    if (row >= N) return;
    float4 v = *(const float4*)(emb + (size_t)row * D + c4);
    short4 o;
    o.x = f2h(v.x); o.y = f2h(v.y); o.z = f2h(v.z); o.w = f2h(v.w);
    *(short4*)(Abf + (size_t)row * 256 + 128 + c4) = o;
    unsigned u = (unsigned)h2e5(o.z) | ((unsigned)h2e5(o.x) << 8) |
                 ((unsigned)h2e5(o.w) << 16) | ((unsigned)h2e5(o.y) << 24);
    *(unsigned*)(X8 + (size_t)row * 128 + c4) = u;
    float4 ch = *(const float4*)(change + (size_t)row * D + c4);
    *(float4*)(out + (size_t)row * D + c4) = ch;
}

// ===========================================================================
// Layer-1 gather: e5m2 x-rows (128B) x f16 rel rows -> f16 agg (packed math).
// Structure: 8-edge batched prologue, four 16-lane groups, clamped tail,
// zero-rel-row masking (verified R10). Packed v_pk_fma_f16 accumulation.
// ===========================================================================
__global__ void gather_conv(const unsigned char* __restrict__ X8,
                            const short* __restrict__ relb,
                            short* __restrict__ Abf,
                            const int* __restrict__ offs,
                            const int* __restrict__ cnt,
                            const int2* __restrict__ pairs, int N, int RZ) {
    int node = blockIdx.x * 4 + (threadIdx.x >> 6);
    if (node >= N) return;
    int lane = threadIdx.x & 63;
    int h = lane >> 4;               // group 0..3
    int c = (lane & 15) * 8;         // 8 elems (= 8 bytes in X8) per lane
    int beg = offs[node], num = cnt[node];
    half2n a0 = u2h2(0u), a1 = u2h2(0u), a2 = u2h2(0u), a3 = u2h2(0u);
    if (num > 0) {
        int ia = h, ib = h + 4;
        int ea = (ia < num) ? ia : (num - 1);
        int2 pa = pairs[beg + ea];
        int ra = (ia < num) ? pa.y : RZ;
        uint2 xa = *(const uint2*)(X8 + (size_t)pa.x * 128 + c);
        uint4 va = *(const uint4*)(relb + (size_t)ra * D + c);
        if (num > 4) {
            int eb = (ib < num) ? ib : (num - 1);
            int2 pb = pairs[beg + eb];
            int rb = (ib < num) ? pb.y : RZ;
            uint2 xb = *(const uint2*)(X8 + (size_t)pb.x * 128 + c);
            uint4 vb = *(const uint4*)(relb + (size_t)rb * D + c);
            e5fma(xa, va, a0, a1, a2, a3);
            e5fma(xb, vb, a0, a1, a2, a3);
        } else {
            e5fma(xa, va, a0, a1, a2, a3);
        }
        for (int i = 8; i < num; i += 4) {           // rare tail
            int ei = i + h;
            int e2 = (ei < num) ? ei : (num - 1);
            int2 pe = pairs[beg + e2];
            int rr = (ei < num) ? pe.y : RZ;
            uint2 xv = *(const uint2*)(X8 + (size_t)pe.x * 128 + c);
            uint4 rv = *(const uint4*)(relb + (size_t)rr * D + c);
            e5fma(xv, rv, a0, a1, a2, a3);
        }
        a0 = red2(a0); a1 = red2(a1); a2 = red2(a2); a3 = red2(a3);
    }
    if (h == 0) {
        float dinv = 1.0f / fmaxf((float)num, 1.0f);
        _Float16 dh = (_Float16)dinv;
        half2n d2 = {dh, dh};
        a0 *= d2; a1 *= d2; a2 *= d2; a3 *= d2;
        uint4 st; st.x = h22u(a0); st.y = h22u(a1); st.z = h22u(a2); st.w = h22u(a3);
        *(uint4*)(Abf + (size_t)node * 256 + c) = st;
    }
}

// ===========================================================================
// Phase-2: nodes [0,N) = layer-2 conv on X8_2 (e5m2 of h1) -> Abf2 agg;
// nodes [N,2N) = jump diffusion from Abf1 x-half (f16) -> dch fp32.
// ===========================================================================
__global__ void gather_phase2(short* __restrict__ Abf2,
                              const unsigned char* __restrict__ X82,
                              const short* __restrict__ Abf1,
                              const short* __restrict__ relb,
                              const float* __restrict__ jwp,
                              const int* __restrict__ offs,
                              const int* __restrict__ cnt,
                              const int2* __restrict__ pairs,
                              float* __restrict__ dch, int N, int RZ) {
    int g = blockIdx.x * 4 + (threadIdx.x >> 6);
    int lane = threadIdx.x & 63;
    int h = lane >> 4;
    int c = (lane & 15) * 8;
    if (g < N) {
        int beg = offs[g], num = cnt[g];
        half2n a0 = u2h2(0u), a1 = u2h2(0u), a2 = u2h2(0u), a3 = u2h2(0u);
        if (num > 0) {
            int ia = h, ib = h + 4;
            int ea = (ia < num) ? ia : (num - 1);
            int2 pa = pairs[beg + ea];
            int ra = (ia < num) ? pa.y : RZ;
            uint2 xa = *(const uint2*)(X82 + (size_t)pa.x * 128 + c);
            uint4 va = *(const uint4*)(relb + (size_t)ra * D + c);
            if (num > 4) {
                int eb = (ib < num) ? ib : (num - 1);
                int2 pb = pairs[beg + eb];
                int rb = (ib < num) ? pb.y : RZ;
                uint2 xb = *(const uint2*)(X82 + (size_t)pb.x * 128 + c);
                uint4 vb = *(const uint4*)(relb + (size_t)rb * D + c);
                e5fma(xa, va, a0, a1, a2, a3);
                e5fma(xb, vb, a0, a1, a2, a3);
            } else {
                e5fma(xa, va, a0, a1, a2, a3);
            }
            for (int i = 8; i < num; i += 4) {
                int ei = i + h;
                int e2 = (ei < num) ? ei : (num - 1);
                int2 pe = pairs[beg + e2];
                int rr = (ei < num) ? pe.y : RZ;
                uint2 xv = *(const uint2*)(X82 + (size_t)pe.x * 128 + c);
                uint4 rv = *(const uint4*)(relb + (size_t)rr * D + c);
                e5fma(xv, rv, a0, a1, a2, a3);
            }
            a0 = red2(a0); a1 = red2(a1); a2 = red2(a2); a3 = red2(a3);
        }
        if (h == 0) {
            float dinv = 1.0f / fmaxf((float)num, 1.0f);
            _Float16 dh = (_Float16)dinv;
            half2n d2 = {dh, dh};
            a0 *= d2; a1 *= d2; a2 *= d2; a3 *= d2;
            uint4 st; st.x = h22u(a0); st.y = h22u(a1); st.z = h22u(a2); st.w = h22u(a3);
            *(uint4*)(Abf2 + (size_t)g * 256 + c) = st;
        }
    } else if (g < 2 * N) {
        int node = g - N;
        int beg = offs[N + node], num = cnt[N + node];
        half2n a0 = u2h2(0u), a1 = u2h2(0u), a2 = u2h2(0u), a3 = u2h2(0u);
        if (num > 0) {
            int ia = h, ib = h + 4;
            int ea = (ia < num) ? ia : (num - 1);
            int2 pa = pairs[beg + ea];
            float wa = (ia < num) ? __int_as_float(pa.y) : 0.f;
            _Float16 wha = (_Float16)wa;
            half2n w2a = {wha, wha};
            uint4 xa = *(const uint4*)(Abf1 + (size_t)pa.x * 256 + 128 + c);
            if (num > 4) {
                int eb = (ib < num) ? ib : (num - 1);
                int2 pb = pairs[beg + eb];
                float wb = (ib < num) ? __int_as_float(pb.y) : 0.f;
                _Float16 whb = (_Float16)wb;
                half2n w2b = {whb, whb};
                uint4 xb = *(const uint4*)(Abf1 + (size_t)pb.x * 256 + 128 + c);
                h16fma(xa, w2a, a0, a1, a2, a3);
                h16fma(xb, w2b, a0, a1, a2, a3);
            } else {
                h16fma(xa, w2a, a0, a1, a2, a3);
            }
            for (int i = 8; i < num; i += 4) {
                int ei = i + h;
                int e2 = (ei < num) ? ei : (num - 1);
                int2 pe = pairs[beg + e2];
                float wgt = (ei < num) ? __int_as_float(pe.y) : 0.f;
                _Float16 wh = (_Float16)wgt;
                half2n w2 = {wh, wh};
                uint4 xv = *(const uint4*)(Abf1 + (size_t)pe.x * 256 + 128 + c);
                h16fma(xv, w2, a0, a1, a2, a3);
            }
            a0 = red2(a0); a1 = red2(a1); a2 = red2(a2); a3 = red2(a3);
        }
        if (h == 0) {
            float jw = jwp[0];
            float* drow = dch + (size_t)node * D + c;
            *(float4*)(drow + 0) = make_float4(jw * (float)a0.x, jw * (float)a0.y,
                                               jw * (float)a1.x, jw * (float)a1.y);
            *(float4*)(drow + 4) = make_float4(jw * (float)a2.x, jw * (float)a2.y,
                                               jw * (float)a3.x, jw * (float)a3.y);
        }
    }
}

// ===========================================================================
// MFMA GEMM (f16): C = Abf[N][256] @ Bpk(256x128); o = f16(x) + res*tanh(C).
// Layer 1: o -> outb x-half (f16) + x8out (e5m2 shadow for phase2 conv).
// Layer 2: o + addin -> outf (fp32).
// ===========================================================================
__launch_bounds__(256)
__global__ void mfma_gemm(const short* __restrict__ Abf,
                          const short* __restrict__ Bpk,
                          const float* __restrict__ resp,
                          short* __restrict__ outb,              // nullable
                          unsigned char* __restrict__ x8out,     // nullable
                          const float* __restrict__ addin,       // nullable
                          float* __restrict__ outf,              // nullable
                          int N) {
    int w = threadIdx.x >> 6;
    int lane = threadIdx.x & 63;
    int rb = (w & 1) * 32;
    int cb = (w >> 1) * 64;
    int row0 = blockIdx.x * 64;
    int m = lane & 15, quad = lane >> 4;

    f32x4 acc[2][4];
#pragma unroll
    for (int rt = 0; rt < 2; rt++)
#pragma unroll
        for (int ct = 0; ct < 4; ct++) acc[rt][ct] = (f32x4)(0.f);

    const short* arow0 = Abf + (size_t)(row0 + rb + m) * 256 + quad * 8;
    const short* arow1 = arow0 + 16 * 256;
    const short* bbase = Bpk + (((size_t)(cb >> 4)) * 8 * 64 + lane) * 8;

#pragma unroll
    for (int kt = 0; kt < 8; kt++) {
        half8v a0 = *(const half8v*)(arow0 + kt * 32);
        half8v a1 = *(const half8v*)(arow1 + kt * 32);
        half8v b[4];
#pragma unroll
        for (int ct = 0; ct < 4; ct++)
            b[ct] = *(const half8v*)(bbase + ((size_t)(ct * 8 + kt)) * 64 * 8);
#pragma unroll
        for (int ct = 0; ct < 4; ct++) {
            acc[0][ct] = __builtin_amdgcn_mfma_f32_16x16x32_f16(a0, b[ct],
                                                                acc[0][ct], 0, 0, 0);
            acc[1][ct] = __builtin_amdgcn_mfma_f32_16x16x32_f16(a1, b[ct],
                                                                acc[1][ct], 0, 0, 0);
        }
    }

    float res = resp[0];
#pragma unroll
    for (int rt = 0; rt < 2; rt++) {
#pragma unroll
        for (int ct = 0; ct < 4; ct++) {
            int colg = cb + ct * 16 + m;
#pragma unroll
            for (int r = 0; r < 4; r++) {
                int rowg = row0 + rb + rt * 16 + quad * 4 + r;
                if (rowg >= N) continue;
                float xr = h2f(Abf[(size_t)rowg * 256 + 128 + colg]);
                float o = xr + res * fast_tanh(acc[rt][ct][r]);
                if (outb != nullptr) {
                    short hx = f2h(o);
                    outb[(size_t)rowg * 256 + 128 + colg] = hx;
                    int d = colg & 3;
                    int pos = 2 * (d & 1) + 1 - (d >> 1);    // {0,1,2,3}->{1,3,0,2}
                    x8out[(size_t)rowg * 128 + (colg & ~3) + pos] = h2e5(hx);
                } else {
                    size_t idx = (size_t)rowg * D + colg;
                    outf[idx] = o + addin[idx];
                }
            }
        }
    }
}

extern "C" void kernel_launch(void* const* d_in, const int* in_sizes, int n_in,
                              void* d_out, int out_size, void* d_ws, size_t ws_size,
                              hipStream_t stream) {
    const float* emb    = (const float*)d_in[0];
    const float* change = (const float*)d_in[1];
    const float* W1     = (const float*)d_in[2];
    const float* Wl1    = (const float*)d_in[3];
    const float* rel1   = (const float*)d_in[4];
    const float* W2     = (const float*)d_in[5];
    const float* Wl2    = (const float*)d_in[6];
    const float* rel2   = (const float*)d_in[7];
    const float* res    = (const float*)d_in[8];
    const float* jw     = (const float*)d_in[9];
    const float* ewj    = (const float*)d_in[10];
    const int*   eidx   = (const int*)d_in[11];
    const int*   etype  = (const int*)d_in[12];
    const int*   ejmp   = (const int*)d_in[13];

    const int ND = in_sizes[0];
    const int N  = ND / D;
    const int E  = in_sizes[12];
    const int EJ = in_sizes[10];
    const int RD = in_sizes[4];              // R*D elements per rel matrix
    const int R  = RD / D;                   // zero row index
    const int NP = ((N + 63) / 64) * 64;
    const int M  = 2 * N;

    float* out = (float*)d_out;          // change passthrough
    float* dch = out + (size_t)ND;       // dchange

    // workspace layout (16B-aligned chunks)
    char* w = (char*)d_ws;
    short* Abf1  = (short*)w;                  w += (size_t)NP * 256 * 2;
    short* Abf2  = (short*)w;                  w += (size_t)NP * 256 * 2;
    short* Bpk1  = (short*)w;                  w += (size_t)64 * 64 * 8 * 2;
    short* Bpk2  = (short*)w;                  w += (size_t)64 * 64 * 8 * 2;
    short* relb1 = (short*)w;                  w += (size_t)(RD + D) * 2;   // +zero row
    short* relb2 = (short*)w;                  w += (size_t)(RD + D) * 2;   // +zero row
    unsigned char* X81 = (unsigned char*)w;    w += (size_t)NP * 128;       // e5m2 emb
    unsigned char* X82 = (unsigned char*)w;    w += (size_t)NP * 128;       // e5m2 h1
    int* cnt     = (int*)w;                    w += (size_t)M * 4;
    int* offs    = (int*)w;                    w += (size_t)M * 4;
    int* cur     = (int*)w;                    w += (size_t)M * 4;
    int* bsum    = (int*)w;                    w += 256 * 4;
    int2* pairs  = (int2*)w;                   w += (size_t)(E + EJ) * 8;

    const int T = 256;
    const int NB2 = (M + 1023) / 1024;
    const int EB  = (E + EJ + T - 1) / T;

    hipMemsetAsync(cnt, 0, (size_t)M * sizeof(int), stream);

    // ---- concatenated CSR build (conv + jump) ----
    hist_both<<<EB, T, 0, stream>>>(eidx + E, ejmp + EJ, cnt, E, EJ, N);
    scan1<<<NB2, 256, 0, stream>>>(cnt, offs, bsum, M);
    scan2<<<1, 256, 0, stream>>>(bsum, NB2);
    scan3<<<(M + T - 1) / T, T, 0, stream>>>(offs, bsum, cur, M);
    fill_both<<<EB, T, 0, stream>>>(eidx, eidx + E, etype, ejmp, ejmp + EJ, ewj,
                                    cur, pairs, E, EJ, N);

    // ---- weight packs (f16) + rel -> f16 (+zero rows) ----
    pack_w<<<128, 64, 0, stream>>>(W1, Wl1, W2, Wl2, Bpk1, Bpk2);
    cvt_rel<<<(RD / 2 + 64 + T - 1) / T, T, 0, stream>>>(rel1, rel2, relb1, relb2, RD);

    // ---- emb -> f16 + e5m2, change -> out ----
    cvt_emb_copy<<<(N * 32 + T - 1) / T, T, 0, stream>>>(emb, change, Abf1, X81, out, N);

    int gatherB  = (N + 3) / 4;
    int gather2B = (M + 3) / 4;
    int gemmB    = NP / 64;

    // ---- layer 1: gather (e5m2 reads) + GEMM (h1 -> Abf2 x-half f16 + X82 e5m2) ----
    gather_conv<<<gatherB, 256, 0, stream>>>(X81, relb1, Abf1, offs, cnt, pairs, N, R);
    mfma_gemm<<<gemmB, 256, 0, stream>>>(Abf1, Bpk1, res, Abf2, X82, nullptr, nullptr, N);

    // ---- layer-2 conv gather (e5m2) + jump gather (f16) ----
    gather_phase2<<<gather2B, 256, 0, stream>>>(Abf2, X82, Abf1, relb2, jw, offs, cnt,
                                                pairs, dch, N, R);

    // ---- layer 2 GEMM: dch = h1 + res*tanh(...) + jump ----
    mfma_gemm<<<gemmB, 256, 0, stream>>>(Abf2, Bpk2, res, nullptr, nullptr, dch, dch, N);
}

// Round 14
// 479.295 us; speedup vs baseline: 1.0912x; 1.0912x over previous
//
#include <hip/hip_runtime.h>
#include <math.h>

#define D 128

typedef __attribute__((ext_vector_type(8))) short short8v;     // raw 16-bit x8
typedef __attribute__((ext_vector_type(4))) float f32x4;       // MFMA acc
typedef _Float16 half2n __attribute__((ext_vector_type(2)));   // packed f16 pair
typedef _Float16 half8v __attribute__((ext_vector_type(8)));   // MFMA f16 frag

__device__ inline short f2h(float f) {                         // f32 -> f16 (RNE)
    _Float16 h = (_Float16)f;
    return __builtin_bit_cast(short, h);
}
__device__ inline float h2f(short s) {
    return (float)__builtin_bit_cast(_Float16, s);
}
// e5m2 = top byte of f16, RNE round on bit 8.
__device__ inline unsigned char h2e5(short hs) {
    unsigned u = (unsigned short)hs;
    u = u + 0x7Fu + ((u >> 8) & 1u);
    return (unsigned char)(u >> 8);
}
__device__ inline half2n u2h2(unsigned u) { return __builtin_bit_cast(half2n, u); }
__device__ inline unsigned h22u(half2n h) { return __builtin_bit_cast(unsigned, h); }

// Fast tanh: one v_exp_f32 + rcp; branch-free, exact at 0/inf.
__device__ inline float fast_tanh(float x) {
    float a = fabsf(x);
    float e = __expf(-2.0f * a);
    float t = (1.0f - e) / (1.0f + e);
    return copysignf(t, x);
}

// e5m2 x-row (8 bytes, order [e2,e0,e3,e1][e6,e4,e7,e5]) x f16 rel pairs -> 4 half2 accs.
__device__ inline void e5fma(uint2 xw, uint4 rw,
                             half2n& a0, half2n& a1, half2n& a2, half2n& a3) {
    a0 += u2h2(xw.x & 0xFF00FF00u) * u2h2(rw.x);          // (e0,e1)
    a1 += u2h2((xw.x << 8) & 0xFF00FF00u) * u2h2(rw.y);   // (e2,e3)
    a2 += u2h2(xw.y & 0xFF00FF00u) * u2h2(rw.z);          // (e4,e5)
    a3 += u2h2((xw.y << 8) & 0xFF00FF00u) * u2h2(rw.w);   // (e6,e7)
}
// f16 x-row x scalar-splat weight -> 4 half2 accs.
__device__ inline void h16fma(uint4 xw, half2n w2,
                              half2n& a0, half2n& a1, half2n& a2, half2n& a3) {
    a0 += u2h2(xw.x) * w2;
    a1 += u2h2(xw.y) * w2;
    a2 += u2h2(xw.z) * w2;
    a3 += u2h2(xw.w) * w2;
}
__device__ inline half2n red2(half2n a) {
    a += u2h2((unsigned)__shfl_xor(__builtin_bit_cast(int, a), 16));
    a += u2h2((unsigned)__shfl_xor(__builtin_bit_cast(int, a), 32));
    return a;
}

// ===========================================================================
// CSR build. hist now RECORDS each edge's slot (old count) -> fill needs no
// atomic: p = offs[dst] + slot[i]. cur[] eliminated.
// ===========================================================================
__global__ void hist_both(const int* __restrict__ dst_e,
                          const int* __restrict__ dst_j,
                          int* __restrict__ cnt, int* __restrict__ slot,
                          int E, int EJ, int N) {
    int i = blockIdx.x * blockDim.x + threadIdx.x;
    if (i < E) slot[i] = atomicAdd(&cnt[dst_e[i]], 1);
    else if (i < E + EJ) slot[i] = atomicAdd(&cnt[N + dst_j[i - E]], 1);
}

__global__ void scan1(const int* __restrict__ cnt, int* __restrict__ offs,
                      int* __restrict__ bsum, int M) {
    __shared__ int sh[256];
    int t = threadIdx.x;
    int base = blockIdx.x * 1024 + t * 4;
    int v0 = 0, v1 = 0, v2 = 0, v3 = 0;
    if (base + 0 < M) v0 = cnt[base + 0];
    if (base + 1 < M) v1 = cnt[base + 1];
    if (base + 2 < M) v2 = cnt[base + 2];
    if (base + 3 < M) v3 = cnt[base + 3];
    int tsum = v0 + v1 + v2 + v3;
    sh[t] = tsum;
    __syncthreads();
    for (int off = 1; off < 256; off <<= 1) {
        int x = (t >= off) ? sh[t - off] : 0;
        __syncthreads();
        sh[t] += x;
        __syncthreads();
    }
    int excl = sh[t] - tsum;
    if (base + 0 < M) offs[base + 0] = excl;
    excl += v0;
    if (base + 1 < M) offs[base + 1] = excl;
    excl += v1;
    if (base + 2 < M) offs[base + 2] = excl;
    excl += v2;
    if (base + 3 < M) offs[base + 3] = excl;
    if (t == 255) bsum[blockIdx.x] = sh[255];
}

__global__ void scan2(int* __restrict__ bsum, int NB) {
    __shared__ int sh[256];
    int t = threadIdx.x;
    int v = (t < NB) ? bsum[t] : 0;
    sh[t] = v;
    __syncthreads();
    for (int off = 1; off < 256; off <<= 1) {
        int x = (t >= off) ? sh[t - off] : 0;
        __syncthreads();
        sh[t] += x;
        __syncthreads();
    }
    if (t < NB) bsum[t] = sh[t] - v;
}

__global__ void scan3(int* __restrict__ offs, const int* __restrict__ bsum, int M) {
    int i = blockIdx.x * blockDim.x + threadIdx.x;
    if (i < M) offs[i] += bsum[i >> 10];
}

// fill without atomics: position = offs[dst] + slot[i] (slot from hist).
__global__ void fill_both(const int* __restrict__ src_e,
                          const int* __restrict__ dst_e,
                          const int* __restrict__ et,
                          const int* __restrict__ src_j,
                          const int* __restrict__ dst_j,
                          const float* __restrict__ ew,
                          const int* __restrict__ offs,
                          const int* __restrict__ slot,
                          int2* __restrict__ pairs,
                          int E, int EJ, int N) {
    int i = blockIdx.x * blockDim.x + threadIdx.x;
    if (i < E) {
        int p = offs[dst_e[i]] + slot[i];
        pairs[p] = make_int2(src_e[i], et[i]);
    } else if (i < E + EJ) {
        int e = i - E;
        int p = offs[N + dst_j[e]] + slot[i];
        pairs[p] = make_int2(src_j[e], __float_as_int(ew[e]));
    }
}

// ===========================================================================
// Weight pack (f16), stacked K: rows 0..127 = W, 128..255 = Wl.
// ===========================================================================
__global__ void pack_w(const float* __restrict__ W1, const float* __restrict__ Wl1,
                       const float* __restrict__ W2, const float* __restrict__ Wl2,
                       short* __restrict__ B1, short* __restrict__ B2) {
    int lane = threadIdx.x;          // 64
    int tile = blockIdx.x & 63;
    const float* W  = (blockIdx.x < 64) ? W1 : W2;
    const float* Wl = (blockIdx.x < 64) ? Wl1 : Wl2;
    short* Bpk      = (blockIdx.x < 64) ? B1 : B2;
    int tn = tile >> 3, tk = tile & 7;
    int n = tn * 16 + (lane & 15);
    int k0 = tk * 32 + (lane >> 4) * 8;
    short* o = Bpk + ((size_t)tile * 64 + lane) * 8;
#pragma unroll
    for (int j = 0; j < 8; j++) {
        int k = k0 + j;
        float f = (k < D) ? W[(size_t)k * D + n] : Wl[(size_t)(k - D) * D + n];
        o[j] = f2h(f);
    }
}

// rel_emb fp32 -> f16, both layers; plus one zero row at index R each.
__global__ void cvt_rel(const float* __restrict__ r1, const float* __restrict__ r2,
                        short* __restrict__ o1, short* __restrict__ o2, int RD) {
    int i = blockIdx.x * blockDim.x + threadIdx.x;   // one thread per 4 elems
    int half = RD >> 2;
    if (i < 2 * half) {
        const float* src = (i < half) ? r1 : r2;
        short* dst = (i < half) ? o1 : o2;
        int j = (i < half) ? i : i - half;
        float4 v = *(const float4*)(src + (size_t)j * 4);
        short4 o;
        o.x = f2h(v.x); o.y = f2h(v.y); o.z = f2h(v.z); o.w = f2h(v.w);
        *(short4*)(dst + (size_t)j * 4) = o;
    } else {
        int extra = i - 2 * half;
        if (extra < 64) {
            short* dst = (extra < 32) ? o1 : o2;
            int j = extra & 31;
            short4 z; z.x = 0; z.y = 0; z.z = 0; z.w = 0;
            *(short4*)(dst + (size_t)RD + j * 4) = z;
        }
    }
}

// emb -> Abf1 x-half (f16) + X8_1 (e5m2, byte order [e2,e0,e3,e1]); change -> out.
__global__ void cvt_emb_copy(const float* __restrict__ emb,
                             const float* __restrict__ change,
                             short* __restrict__ Abf,
                             unsigned char* __restrict__ X8,
                             float* __restrict__ out, int N) {
    int i = blockIdx.x * blockDim.x + threadIdx.x;   // one thread per 4 elems
    int row = i >> 5;
    int c4 = (i & 31) * 4;
    if (row >= N) return;
    float4 v = *(const float4*)(emb + (size_t)row * D + c4);
    short4 o;
    o.x = f2h(v.x); o.y = f2h(v.y); o.z = f2h(v.z); o.w = f2h(v.w);
    *(short4*)(Abf + (size_t)row * 256 + 128 + c4) = o;
    unsigned u = (unsigned)h2e5(o.z) | ((unsigned)h2e5(o.x) << 8) |
                 ((unsigned)h2e5(o.w) << 16) | ((unsigned)h2e5(o.y) << 24);
    *(unsigned*)(X8 + (size_t)row * 128 + c4) = u;
    float4 ch = *(const float4*)(change + (size_t)row * D + c4);
    *(float4*)(out + (size_t)row * D + c4) = ch;
}

// ===========================================================================
// Conv gather (layer L): e5m2 x-rows x f16 rel -> f16 agg into Abf cols 0..127.
// 8-edge batched prologue, four 16-lane groups, clamped tail, zero-rel masking.
// ===========================================================================
__global__ void gather_conv(const unsigned char* __restrict__ X8,
                            const short* __restrict__ relb,
                            short* __restrict__ Abf,
                            const int* __restrict__ offs,
                            const int* __restrict__ cnt,
                            const int2* __restrict__ pairs, int N, int RZ) {
    int node = blockIdx.x * 4 + (threadIdx.x >> 6);
    if (node >= N) return;
    int lane = threadIdx.x & 63;
    int h = lane >> 4;               // group 0..3
    int c = (lane & 15) * 8;         // 8 elems per lane
    int beg = offs[node], num = cnt[node];
    half2n a0 = u2h2(0u), a1 = u2h2(0u), a2 = u2h2(0u), a3 = u2h2(0u);
    if (num > 0) {
        int ia = h, ib = h + 4;
        int ea = (ia < num) ? ia : (num - 1);
        int2 pa = pairs[beg + ea];
        int ra = (ia < num) ? pa.y : RZ;
        uint2 xa = *(const uint2*)(X8 + (size_t)pa.x * 128 + c);
        uint4 va = *(const uint4*)(relb + (size_t)ra * D + c);
        if (num > 4) {
            int eb = (ib < num) ? ib : (num - 1);
            int2 pb = pairs[beg + eb];
            int rb = (ib < num) ? pb.y : RZ;
            uint2 xb = *(const uint2*)(X8 + (size_t)pb.x * 128 + c);
            uint4 vb = *(const uint4*)(relb + (size_t)rb * D + c);
            e5fma(xa, va, a0, a1, a2, a3);
            e5fma(xb, vb, a0, a1, a2, a3);
        } else {
            e5fma(xa, va, a0, a1, a2, a3);
        }
        for (int i = 8; i < num; i += 4) {           // rare tail
            int ei = i + h;
            int e2 = (ei < num) ? ei : (num - 1);
            int2 pe = pairs[beg + e2];
            int rr = (ei < num) ? pe.y : RZ;
            uint2 xv = *(const uint2*)(X8 + (size_t)pe.x * 128 + c);
            uint4 rv = *(const uint4*)(relb + (size_t)rr * D + c);
            e5fma(xv, rv, a0, a1, a2, a3);
        }
        a0 = red2(a0); a1 = red2(a1); a2 = red2(a2); a3 = red2(a3);
    }
    if (h == 0) {
        float dinv = 1.0f / fmaxf((float)num, 1.0f);
        _Float16 dh = (_Float16)dinv;
        half2n d2 = {dh, dh};
        a0 *= d2; a1 *= d2; a2 *= d2; a3 *= d2;
        uint4 st; st.x = h22u(a0); st.y = h22u(a1); st.z = h22u(a2); st.w = h22u(a3);
        *(uint4*)(Abf + (size_t)node * 256 + c) = st;
    }
}

// ===========================================================================
// Jump gather (split out for per-dispatch counters): f16 emb rows (Abf1 x-half)
// weighted-sum -> jh (f16, 25.6 MB writes instead of 51.2 fp32).
// ===========================================================================
__global__ void gather_jump(const short* __restrict__ Abf1,
                            short* __restrict__ jh,
                            const int* __restrict__ offs,
                            const int* __restrict__ cnt,
                            const int2* __restrict__ pairs, int N) {
    int node = blockIdx.x * 4 + (threadIdx.x >> 6);
    if (node >= N) return;
    int lane = threadIdx.x & 63;
    int h = lane >> 4;
    int c = (lane & 15) * 8;
    int beg = offs[N + node], num = cnt[N + node];
    half2n a0 = u2h2(0u), a1 = u2h2(0u), a2 = u2h2(0u), a3 = u2h2(0u);
    if (num > 0) {
        int ia = h, ib = h + 4;
        int ea = (ia < num) ? ia : (num - 1);
        int2 pa = pairs[beg + ea];
        float wa = (ia < num) ? __int_as_float(pa.y) : 0.f;
        _Float16 wha = (_Float16)wa;
        half2n w2a = {wha, wha};
        uint4 xa = *(const uint4*)(Abf1 + (size_t)pa.x * 256 + 128 + c);
        if (num > 4) {
            int eb = (ib < num) ? ib : (num - 1);
            int2 pb = pairs[beg + eb];
            float wb = (ib < num) ? __int_as_float(pb.y) : 0.f;
            _Float16 whb = (_Float16)wb;
            half2n w2b = {whb, whb};
            uint4 xb = *(const uint4*)(Abf1 + (size_t)pb.x * 256 + 128 + c);
            h16fma(xa, w2a, a0, a1, a2, a3);
            h16fma(xb, w2b, a0, a1, a2, a3);
        } else {
            h16fma(xa, w2a, a0, a1, a2, a3);
        }
        for (int i = 8; i < num; i += 4) {
            int ei = i + h;
            int e2 = (ei < num) ? ei : (num - 1);
            int2 pe = pairs[beg + e2];
            float wgt = (ei < num) ? __int_as_float(pe.y) : 0.f;
            _Float16 wh = (_Float16)wgt;
            half2n w2 = {wh, wh};
            uint4 xv = *(const uint4*)(Abf1 + (size_t)pe.x * 256 + 128 + c);
            h16fma(xv, w2, a0, a1, a2, a3);
        }
        a0 = red2(a0); a1 = red2(a1); a2 = red2(a2); a3 = red2(a3);
    }
    if (h == 0) {
        uint4 st; st.x = h22u(a0); st.y = h22u(a1); st.z = h22u(a2); st.w = h22u(a3);
        *(uint4*)(jh + (size_t)node * 128 + c) = st;
    }
}

// ===========================================================================
// MFMA GEMM (f16): C = Abf[N][256] @ Bpk(256x128); o = f16(x) + res*tanh(C).
// Layer 1: o -> outb x-half (f16) + x8out (e5m2 shadow for layer-2 conv).
// Layer 2: o + jw*f16(jh) -> outf (fp32).
// ===========================================================================
__launch_bounds__(256)
__global__ void mfma_gemm(const short* __restrict__ Abf,
                          const short* __restrict__ Bpk,
                          const float* __restrict__ resp,
                          short* __restrict__ outb,              // nullable
                          unsigned char* __restrict__ x8out,     // nullable
                          const short* __restrict__ addin_h,     // nullable (f16)
                          const float* __restrict__ jwp,         // nullable
                          float* __restrict__ outf,              // nullable
                          int N) {
    int w = threadIdx.x >> 6;
    int lane = threadIdx.x & 63;
    int rb = (w & 1) * 32;
    int cb = (w >> 1) * 64;
    int row0 = blockIdx.x * 64;
    int m = lane & 15, quad = lane >> 4;

    f32x4 acc[2][4];
#pragma unroll
    for (int rt = 0; rt < 2; rt++)
#pragma unroll
        for (int ct = 0; ct < 4; ct++) acc[rt][ct] = (f32x4)(0.f);

    const short* arow0 = Abf + (size_t)(row0 + rb + m) * 256 + quad * 8;
    const short* arow1 = arow0 + 16 * 256;
    const short* bbase = Bpk + (((size_t)(cb >> 4)) * 8 * 64 + lane) * 8;

#pragma unroll
    for (int kt = 0; kt < 8; kt++) {
        half8v a0 = *(const half8v*)(arow0 + kt * 32);
        half8v a1 = *(const half8v*)(arow1 + kt * 32);
        half8v b[4];
#pragma unroll
        for (int ct = 0; ct < 4; ct++)
            b[ct] = *(const half8v*)(bbase + ((size_t)(ct * 8 + kt)) * 64 * 8);
#pragma unroll
        for (int ct = 0; ct < 4; ct++) {
            acc[0][ct] = __builtin_amdgcn_mfma_f32_16x16x32_f16(a0, b[ct],
                                                                acc[0][ct], 0, 0, 0);
            acc[1][ct] = __builtin_amdgcn_mfma_f32_16x16x32_f16(a1, b[ct],
                                                                acc[1][ct], 0, 0, 0);
        }
    }

    float res = resp[0];
    float jw = (jwp != nullptr) ? jwp[0] : 0.f;
#pragma unroll
    for (int rt = 0; rt < 2; rt++) {
#pragma unroll
        for (int ct = 0; ct < 4; ct++) {
            int colg = cb + ct * 16 + m;
#pragma unroll
            for (int r = 0; r < 4; r++) {
                int rowg = row0 + rb + rt * 16 + quad * 4 + r;
                if (rowg >= N) continue;
                float xr = h2f(Abf[(size_t)rowg * 256 + 128 + colg]);
                float o = xr + res * fast_tanh(acc[rt][ct][r]);
                if (outb != nullptr) {
                    short hx = f2h(o);
                    outb[(size_t)rowg * 256 + 128 + colg] = hx;
                    int d = colg & 3;
                    int pos = 2 * (d & 1) + 1 - (d >> 1);    // {0,1,2,3}->{1,3,0,2}
                    x8out[(size_t)rowg * 128 + (colg & ~3) + pos] = h2e5(hx);
                } else {
                    size_t idx = (size_t)rowg * D + colg;
                    outf[idx] = o + jw * h2f(addin_h[idx]);
                }
            }
        }
    }
}

extern "C" void kernel_launch(void* const* d_in, const int* in_sizes, int n_in,
                              void* d_out, int out_size, void* d_ws, size_t ws_size,
                              hipStream_t stream) {
    const float* emb    = (const float*)d_in[0];
    const float* change = (const float*)d_in[1];
    const float* W1     = (const float*)d_in[2];
    const float* Wl1    = (const float*)d_in[3];
    const float* rel1   = (const float*)d_in[4];
    const float* W2     = (const float*)d_in[5];
    const float* Wl2    = (const float*)d_in[6];
    const float* rel2   = (const float*)d_in[7];
    const float* res    = (const float*)d_in[8];
    const float* jw     = (const float*)d_in[9];
    const float* ewj    = (const float*)d_in[10];
    const int*   eidx   = (const int*)d_in[11];
    const int*   etype  = (const int*)d_in[12];
    const int*   ejmp   = (const int*)d_in[13];

    const int ND = in_sizes[0];
    const int N  = ND / D;
    const int E  = in_sizes[12];
    const int EJ = in_sizes[10];
    const int RD = in_sizes[4];              // R*D elements per rel matrix
    const int R  = RD / D;                   // zero row index
    const int NP = ((N + 63) / 64) * 64;
    const int M  = 2 * N;

    float* out = (float*)d_out;          // change passthrough
    float* dch = out + (size_t)ND;       // dchange

    // workspace layout (16B-aligned chunks)
    char* w = (char*)d_ws;
    short* Abf1  = (short*)w;                  w += (size_t)NP * 256 * 2;
    short* Abf2  = (short*)w;                  w += (size_t)NP * 256 * 2;
    short* Bpk1  = (short*)w;                  w += (size_t)64 * 64 * 8 * 2;
    short* Bpk2  = (short*)w;                  w += (size_t)64 * 64 * 8 * 2;
    short* relb1 = (short*)w;                  w += (size_t)(RD + D) * 2;   // +zero row
    short* relb2 = (short*)w;                  w += (size_t)(RD + D) * 2;   // +zero row
    unsigned char* X81 = (unsigned char*)w;    w += (size_t)NP * 128;       // e5m2 emb
    unsigned char* X82 = (unsigned char*)w;    w += (size_t)NP * 128;       // e5m2 h1
    short* jh    = (short*)w;                  w += (size_t)NP * 128 * 2;   // f16 jump
    int* cnt     = (int*)w;                    w += (size_t)M * 4;
    int* offs    = (int*)w;                    w += (size_t)M * 4;
    int* bsum    = (int*)w;                    w += 256 * 4;
    int* slot    = (int*)w;                    w += (size_t)(E + EJ) * 4;
    int2* pairs  = (int2*)w;                   w += (size_t)(E + EJ) * 8;

    const int T = 256;
    const int NB2 = (M + 1023) / 1024;
    const int EB  = (E + EJ + T - 1) / T;

    hipMemsetAsync(cnt, 0, (size_t)M * sizeof(int), stream);

    // ---- concatenated CSR build (conv + jump), slot-recorded, no fill atomics ----
    hist_both<<<EB, T, 0, stream>>>(eidx + E, ejmp + EJ, cnt, slot, E, EJ, N);
    scan1<<<NB2, 256, 0, stream>>>(cnt, offs, bsum, M);
    scan2<<<1, 256, 0, stream>>>(bsum, NB2);
    scan3<<<(M + T - 1) / T, T, 0, stream>>>(offs, bsum, M);
    fill_both<<<EB, T, 0, stream>>>(eidx, eidx + E, etype, ejmp, ejmp + EJ, ewj,
                                    offs, slot, pairs, E, EJ, N);

    // ---- weight packs (f16) + rel -> f16 (+zero rows) ----
    pack_w<<<128, 64, 0, stream>>>(W1, Wl1, W2, Wl2, Bpk1, Bpk2);
    cvt_rel<<<(RD / 2 + 64 + T - 1) / T, T, 0, stream>>>(rel1, rel2, relb1, relb2, RD);

    // ---- emb -> f16 + e5m2, change -> out ----
    cvt_emb_copy<<<(N * 32 + T - 1) / T, T, 0, stream>>>(emb, change, Abf1, X81, out, N);

    int gatherB = (N + 3) / 4;
    int gemmB   = NP / 64;

    // ---- jump gather (independent of conv layers; emb-based) -> jh f16 ----
    gather_jump<<<gatherB, 256, 0, stream>>>(Abf1, jh, offs, cnt, pairs, N);

    // ---- layer 1: conv gather + GEMM (h1 -> Abf2 x-half f16 + X82 e5m2) ----
    gather_conv<<<gatherB, 256, 0, stream>>>(X81, relb1, Abf1, offs, cnt, pairs, N, R);
    mfma_gemm<<<gemmB, 256, 0, stream>>>(Abf1, Bpk1, res, Abf2, X82,
                                         nullptr, nullptr, nullptr, N);

    // ---- layer-2 conv gather ----
    gather_conv<<<gatherB, 256, 0, stream>>>(X82, relb2, Abf2, offs, cnt, pairs, N, R);

    // ---- layer 2 GEMM: dch = h1 + res*tanh(...) + jw*jh ----
    mfma_gemm<<<gemmB, 256, 0, stream>>>(Abf2, Bpk2, res, nullptr, nullptr,
                                         jh, jw, dch, N);
}

// Round 17
// 460.175 us; speedup vs baseline: 1.1366x; 1.0416x over previous
//
#include <hip/hip_runtime.h>
#include <math.h>

#define D 128

typedef __attribute__((ext_vector_type(8))) short short8v;     // raw 16-bit x8
typedef __attribute__((ext_vector_type(4))) float f32x4;       // MFMA acc / NT vec
typedef _Float16 half2n __attribute__((ext_vector_type(2)));   // packed f16 pair
typedef _Float16 half8v __attribute__((ext_vector_type(8)));   // MFMA f16 frag

__device__ inline short f2h(float f) {                         // f32 -> f16 (RNE)
    _Float16 h = (_Float16)f;
    return __builtin_bit_cast(short, h);
}
__device__ inline float h2f(short s) {
    return (float)__builtin_bit_cast(_Float16, s);
}
// e5m2 = top byte of f16, RNE round on bit 8.
__device__ inline unsigned char h2e5(short hs) {
    unsigned u = (unsigned short)hs;
    u = u + 0x7Fu + ((u >> 8) & 1u);
    return (unsigned char)(u >> 8);
}
__device__ inline half2n u2h2(unsigned u) { return __builtin_bit_cast(half2n, u); }
__device__ inline unsigned h22u(half2n h) { return __builtin_bit_cast(unsigned, h); }

// Fast tanh: one v_exp_f32 + rcp; branch-free, exact at 0/inf.
__device__ inline float fast_tanh(float x) {
    float a = fabsf(x);
    float e = __expf(-2.0f * a);
    float t = (1.0f - e) / (1.0f + e);
    return copysignf(t, x);
}

// e5m2 x-row (8 bytes, order [e2,e0,e3,e1][e6,e4,e7,e5]) x f16 rel pairs -> 4 half2 accs.
__device__ inline void e5fma(uint2 xw, uint4 rw,
                             half2n& a0, half2n& a1, half2n& a2, half2n& a3) {
    a0 += u2h2(xw.x & 0xFF00FF00u) * u2h2(rw.x);          // (e0,e1)
    a1 += u2h2((xw.x << 8) & 0xFF00FF00u) * u2h2(rw.y);   // (e2,e3)
    a2 += u2h2(xw.y & 0xFF00FF00u) * u2h2(rw.z);          // (e4,e5)
    a3 += u2h2((xw.y << 8) & 0xFF00FF00u) * u2h2(rw.w);   // (e6,e7)
}
// f16 x-row x scalar-splat weight -> 4 half2 accs.
__device__ inline void h16fma(uint4 xw, half2n w2,
                              half2n& a0, half2n& a1, half2n& a2, half2n& a3) {
    a0 += u2h2(xw.x) * w2;
    a1 += u2h2(xw.y) * w2;
    a2 += u2h2(xw.z) * w2;
    a3 += u2h2(xw.w) * w2;
}
__device__ inline half2n red2(half2n a) {
    a += u2h2((unsigned)__shfl_xor(__builtin_bit_cast(int, a), 16));
    a += u2h2((unsigned)__shfl_xor(__builtin_bit_cast(int, a), 32));
    return a;
}

// ===========================================================================
// CSR build. hist RECORDS each edge's slot (old count) -> fill needs no
// atomic: p = offs[dst] + slot[i].
// ===========================================================================
__global__ void hist_both(const int* __restrict__ dst_e,
                          const int* __restrict__ dst_j,
                          int* __restrict__ cnt, int* __restrict__ slot,
                          int E, int EJ, int N) {
    int i = blockIdx.x * blockDim.x + threadIdx.x;
    if (i < E) slot[i] = atomicAdd(&cnt[dst_e[i]], 1);
    else if (i < E + EJ) slot[i] = atomicAdd(&cnt[N + dst_j[i - E]], 1);
}

__global__ void scan1(const int* __restrict__ cnt, int* __restrict__ offs,
                      int* __restrict__ bsum, int M) {
    __shared__ int sh[256];
    int t = threadIdx.x;
    int base = blockIdx.x * 1024 + t * 4;
    int v0 = 0, v1 = 0, v2 = 0, v3 = 0;
    if (base + 0 < M) v0 = cnt[base + 0];
    if (base + 1 < M) v1 = cnt[base + 1];
    if (base + 2 < M) v2 = cnt[base + 2];
    if (base + 3 < M) v3 = cnt[base + 3];
    int tsum = v0 + v1 + v2 + v3;
    sh[t] = tsum;
    __syncthreads();
    for (int off = 1; off < 256; off <<= 1) {
        int x = (t >= off) ? sh[t - off] : 0;
        __syncthreads();
        sh[t] += x;
        __syncthreads();
    }
    int excl = sh[t] - tsum;
    if (base + 0 < M) offs[base + 0] = excl;
    excl += v0;
    if (base + 1 < M) offs[base + 1] = excl;
    excl += v1;
    if (base + 2 < M) offs[base + 2] = excl;
    excl += v2;
    if (base + 3 < M) offs[base + 3] = excl;
    if (t == 255) bsum[blockIdx.x] = sh[255];
}

__global__ void scan2(int* __restrict__ bsum, int NB) {
    __shared__ int sh[256];
    int t = threadIdx.x;
    int v = (t < NB) ? bsum[t] : 0;
    sh[t] = v;
    __syncthreads();
    for (int off = 1; off < 256; off <<= 1) {
        int x = (t >= off) ? sh[t - off] : 0;
        __syncthreads();
        sh[t] += x;
        __syncthreads();
    }
    if (t < NB) bsum[t] = sh[t] - v;
}

__global__ void scan3(int* __restrict__ offs, const int* __restrict__ bsum, int M) {
    int i = blockIdx.x * blockDim.x + threadIdx.x;
    if (i < M) offs[i] += bsum[i >> 10];
}

// fill without atomics: position = offs[dst] + slot[i] (slot from hist).
__global__ void fill_both(const int* __restrict__ src_e,
                          const int* __restrict__ dst_e,
                          const int* __restrict__ et,
                          const int* __restrict__ src_j,
                          const int* __restrict__ dst_j,
                          const float* __restrict__ ew,
                          const int* __restrict__ offs,
                          const int* __restrict__ slot,
                          int2* __restrict__ pairs,
                          int E, int EJ, int N) {
    int i = blockIdx.x * blockDim.x + threadIdx.x;
    if (i < E) {
        int p = offs[dst_e[i]] + slot[i];
        pairs[p] = make_int2(src_e[i], et[i]);
    } else if (i < E + EJ) {
        int e = i - E;
        int p = offs[N + dst_j[e]] + slot[i];
        pairs[p] = make_int2(src_j[e], __float_as_int(ew[e]));
    }
}

// ===========================================================================
// Weight pack (f16), stacked K: rows 0..127 = W, 128..255 = Wl.
// ===========================================================================
__global__ void pack_w(const float* __restrict__ W1, const float* __restrict__ Wl1,
                       const float* __restrict__ W2, const float* __restrict__ Wl2,
                       short* __restrict__ B1, short* __restrict__ B2) {
    int lane = threadIdx.x;          // 64
    int tile = blockIdx.x & 63;
    const float* W  = (blockIdx.x < 64) ? W1 : W2;
    const float* Wl = (blockIdx.x < 64) ? Wl1 : Wl2;
    short* Bpk      = (blockIdx.x < 64) ? B1 : B2;
    int tn = tile >> 3, tk = tile & 7;
    int n = tn * 16 + (lane & 15);
    int k0 = tk * 32 + (lane >> 4) * 8;
    short* o = Bpk + ((size_t)tile * 64 + lane) * 8;
#pragma unroll
    for (int j = 0; j < 8; j++) {
        int k = k0 + j;
        float f = (k < D) ? W[(size_t)k * D + n] : Wl[(size_t)(k - D) * D + n];
        o[j] = f2h(f);
    }
}

// rel_emb fp32 -> f16, both layers; plus one zero row at index R each.
__global__ void cvt_rel(const float* __restrict__ r1, const float* __restrict__ r2,
                        short* __restrict__ o1, short* __restrict__ o2, int RD) {
    int i = blockIdx.x * blockDim.x + threadIdx.x;   // one thread per 4 elems
    int half = RD >> 2;
    if (i < 2 * half) {
        const float* src = (i < half) ? r1 : r2;
        short* dst = (i < half) ? o1 : o2;
        int j = (i < half) ? i : i - half;
        float4 v = *(const float4*)(src + (size_t)j * 4);
        short4 o;
        o.x = f2h(v.x); o.y = f2h(v.y); o.z = f2h(v.z); o.w = f2h(v.w);
        *(short4*)(dst + (size_t)j * 4) = o;
    } else {
        int extra = i - 2 * half;
        if (extra < 64) {
            short* dst = (extra < 32) ? o1 : o2;
            int j = extra & 31;
            short4 z; z.x = 0; z.y = 0; z.z = 0; z.w = 0;
            *(short4*)(dst + (size_t)RD + j * 4) = z;
        }
    }
}

// emb -> Abf1 x-half (f16) + X8_1 (e5m2); change -> out.
// emb/change are touch-once: NT loads. out is touch-once: NT store
// (keeps L3 free for the gather working sets X8*/Abf*).
// NT builtins need ext_vector types (f32x4), not HIP's float4 class.
__global__ void cvt_emb_copy(const float* __restrict__ emb,
                             const float* __restrict__ change,
                             short* __restrict__ Abf,
                             unsigned char* __restrict__ X8,
                             float* __restrict__ out, int N) {
    int i = blockIdx.x * blockDim.x + threadIdx.x;   // one thread per 4 elems
    int row = i >> 5;
    int c4 = (i & 31) * 4;
    if (row >= N) return;
    f32x4 v = __builtin_nontemporal_load((const f32x4*)(emb + (size_t)row * D + c4));
    short4 o;
    o.x = f2h(v.x); o.y = f2h(v.y); o.z = f2h(v.z); o.w = f2h(v.w);
    *(short4*)(Abf + (size_t)row * 256 + 128 + c4) = o;
    unsigned u = (unsigned)h2e5(o.z) | ((unsigned)h2e5(o.x) << 8) |
                 ((unsigned)h2e5(o.w) << 16) | ((unsigned)h2e5(o.y) << 24);
    *(unsigned*)(X8 + (size_t)row * 128 + c4) = u;
    f32x4 ch = __builtin_nontemporal_load((const f32x4*)(change + (size_t)row * D + c4));
    __builtin_nontemporal_store(ch, (f32x4*)(out + (size_t)row * D + c4));
}

// ===========================================================================
// Conv gather (layer L): e5m2 x-rows x f16 rel -> f16 agg into Abf cols 0..127.
// 8-edge batched prologue, four 16-lane groups, clamped tail, zero-rel masking.
// ===========================================================================
__global__ void gather_conv(const unsigned char* __restrict__ X8,
                            const short* __restrict__ relb,
                            short* __restrict__ Abf,
                            const int* __restrict__ offs,
                            const int* __restrict__ cnt,
                            const int2* __restrict__ pairs, int N, int RZ) {
    int node = blockIdx.x * 4 + (threadIdx.x >> 6);
    if (node >= N) return;
    int lane = threadIdx.x & 63;
    int h = lane >> 4;               // group 0..3
    int c = (lane & 15) * 8;         // 8 elems per lane
    int beg = offs[node], num = cnt[node];
    half2n a0 = u2h2(0u), a1 = u2h2(0u), a2 = u2h2(0u), a3 = u2h2(0u);
    if (num > 0) {
        int ia = h, ib = h + 4;
        int ea = (ia < num) ? ia : (num - 1);
        int2 pa = pairs[beg + ea];
        int ra = (ia < num) ? pa.y : RZ;
        uint2 xa = *(const uint2*)(X8 + (size_t)pa.x * 128 + c);
        uint4 va = *(const uint4*)(relb + (size_t)ra * D + c);
        if (num > 4) {
            int eb = (ib < num) ? ib : (num - 1);
            int2 pb = pairs[beg + eb];
            int rb = (ib < num) ? pb.y : RZ;
            uint2 xb = *(const uint2*)(X8 + (size_t)pb.x * 128 + c);
            uint4 vb = *(const uint4*)(relb + (size_t)rb * D + c);
            e5fma(xa, va, a0, a1, a2, a3);
            e5fma(xb, vb, a0, a1, a2, a3);
        } else {
            e5fma(xa, va, a0, a1, a2, a3);
        }
        for (int i = 8; i < num; i += 4) {           // rare tail
            int ei = i + h;
            int e2 = (ei < num) ? ei : (num - 1);
            int2 pe = pairs[beg + e2];
            int rr = (ei < num) ? pe.y : RZ;
            uint2 xv = *(const uint2*)(X8 + (size_t)pe.x * 128 + c);
            uint4 rv = *(const uint4*)(relb + (size_t)rr * D + c);
            e5fma(xv, rv, a0, a1, a2, a3);
        }
        a0 = red2(a0); a1 = red2(a1); a2 = red2(a2); a3 = red2(a3);
    }
    if (h == 0) {
        float dinv = 1.0f / fmaxf((float)num, 1.0f);
        _Float16 dh = (_Float16)dinv;
        half2n d2 = {dh, dh};
        a0 *= d2; a1 *= d2; a2 *= d2; a3 *= d2;
        uint4 st; st.x = h22u(a0); st.y = h22u(a1); st.z = h22u(a2); st.w = h22u(a3);
        *(uint4*)(Abf + (size_t)node * 256 + c) = st;
    }
}

// ===========================================================================
// Jump gather: f16 emb rows (Abf1 x-half) weighted-sum -> jh (f16).
// ===========================================================================
__global__ void gather_jump(const short* __restrict__ Abf1,
                            short* __restrict__ jh,
                            const int* __restrict__ offs,
                            const int* __restrict__ cnt,
                            const int2* __restrict__ pairs, int N) {
    int node = blockIdx.x * 4 + (threadIdx.x >> 6);
    if (node >= N) return;
    int lane = threadIdx.x & 63;
    int h = lane >> 4;
    int c = (lane & 15) * 8;
    int beg = offs[N + node], num = cnt[N + node];
    half2n a0 = u2h2(0u), a1 = u2h2(0u), a2 = u2h2(0u), a3 = u2h2(0u);
    if (num > 0) {
        int ia = h, ib = h + 4;
        int ea = (ia < num) ? ia : (num - 1);
        int2 pa = pairs[beg + ea];
        float wa = (ia < num) ? __int_as_float(pa.y) : 0.f;
        _Float16 wha = (_Float16)wa;
        half2n w2a = {wha, wha};
        uint4 xa = *(const uint4*)(Abf1 + (size_t)pa.x * 256 + 128 + c);
        if (num > 4) {
            int eb = (ib < num) ? ib : (num - 1);
            int2 pb = pairs[beg + eb];
            float wb = (ib < num) ? __int_as_float(pb.y) : 0.f;
            _Float16 whb = (_Float16)wb;
            half2n w2b = {whb, whb};
            uint4 xb = *(const uint4*)(Abf1 + (size_t)pb.x * 256 + 128 + c);
            h16fma(xa, w2a, a0, a1, a2, a3);
            h16fma(xb, w2b, a0, a1, a2, a3);
        } else {
            h16fma(xa, w2a, a0, a1, a2, a3);
        }
        for (int i = 8; i < num; i += 4) {
            int ei = i + h;
            int e2 = (ei < num) ? ei : (num - 1);
            int2 pe = pairs[beg + e2];
            float wgt = (ei < num) ? __int_as_float(pe.y) : 0.f;
            _Float16 wh = (_Float16)wgt;
            half2n w2 = {wh, wh};
            uint4 xv = *(const uint4*)(Abf1 + (size_t)pe.x * 256 + 128 + c);
            h16fma(xv, w2, a0, a1, a2, a3);
        }
        a0 = red2(a0); a1 = red2(a1); a2 = red2(a2); a3 = red2(a3);
    }
    if (h == 0) {
        uint4 st; st.x = h22u(a0); st.y = h22u(a1); st.z = h22u(a2); st.w = h22u(a3);
        *(uint4*)(jh + (size_t)node * 128 + c) = st;
    }
}

// ===========================================================================
// MFMA GEMM (f16): C = Abf[N][256] @ Bpk(256x128); o = f16(x) + res*tanh(C).
// Layer 1: o -> outb x-half (f16) + x8out (e5m2 shadow for layer-2 conv).
// Layer 2: o + jw*f16(jh) -> outf (fp32, NT store: touch-once output).
// ===========================================================================
__launch_bounds__(256)
__global__ void mfma_gemm(const short* __restrict__ Abf,
                          const short* __restrict__ Bpk,
                          const float* __restrict__ resp,
                          short* __restrict__ outb,              // nullable
                          unsigned char* __restrict__ x8out,     // nullable
                          const short* __restrict__ addin_h,     // nullable (f16)
                          const float* __restrict__ jwp,         // nullable
                          float* __restrict__ outf,              // nullable
                          int N) {
    int w = threadIdx.x >> 6;
    int lane = threadIdx.x & 63;
    int rb = (w & 1) * 32;
    int cb = (w >> 1) * 64;
    int row0 = blockIdx.x * 64;
    int m = lane & 15, quad = lane >> 4;

    f32x4 acc[2][4];
#pragma unroll
    for (int rt = 0; rt < 2; rt++)
#pragma unroll
        for (int ct = 0; ct < 4; ct++) acc[rt][ct] = (f32x4)(0.f);

    const short* arow0 = Abf + (size_t)(row0 + rb + m) * 256 + quad * 8;
    const short* arow1 = arow0 + 16 * 256;
    const short* bbase = Bpk + (((size_t)(cb >> 4)) * 8 * 64 + lane) * 8;

#pragma unroll
    for (int kt = 0; kt < 8; kt++) {
        half8v a0 = *(const half8v*)(arow0 + kt * 32);
        half8v a1 = *(const half8v*)(arow1 + kt * 32);
        half8v b[4];
#pragma unroll
        for (int ct = 0; ct < 4; ct++)
            b[ct] = *(const half8v*)(bbase + ((size_t)(ct * 8 + kt)) * 64 * 8);
#pragma unroll
        for (int ct = 0; ct < 4; ct++) {
            acc[0][ct] = __builtin_amdgcn_mfma_f32_16x16x32_f16(a0, b[ct],
                                                                acc[0][ct], 0, 0, 0);
            acc[1][ct] = __builtin_amdgcn_mfma_f32_16x16x32_f16(a1, b[ct],
                                                                acc[1][ct], 0, 0, 0);
        }
    }

    float res = resp[0];
    float jw = (jwp != nullptr) ? jwp[0] : 0.f;
#pragma unroll
    for (int rt = 0; rt < 2; rt++) {
#pragma unroll
        for (int ct = 0; ct < 4; ct++) {
            int colg = cb + ct * 16 + m;
#pragma unroll
            for (int r = 0; r < 4; r++) {
                int rowg = row0 + rb + rt * 16 + quad * 4 + r;
                if (rowg >= N) continue;
                float xr = h2f(Abf[(size_t)rowg * 256 + 128 + colg]);
                float o = xr + res * fast_tanh(acc[rt][ct][r]);
                if (outb != nullptr) {
                    short hx = f2h(o);
                    outb[(size_t)rowg * 256 + 128 + colg] = hx;
                    int d = colg & 3;
                    int pos = 2 * (d & 1) + 1 - (d >> 1);    // {0,1,2,3}->{1,3,0,2}
                    x8out[(size_t)rowg * 128 + (colg & ~3) + pos] = h2e5(hx);
                } else {
                    size_t idx = (size_t)rowg * D + colg;
                    float val = o + jw * h2f(addin_h[idx]);
                    __builtin_nontemporal_store(val, &outf[idx]);
                }
            }
        }
    }
}

extern "C" void kernel_launch(void* const* d_in, const int* in_sizes, int n_in,
                              void* d_out, int out_size, void* d_ws, size_t ws_size,
                              hipStream_t stream) {
    const float* emb    = (const float*)d_in[0];
    const float* change = (const float*)d_in[1];
    const float* W1     = (const float*)d_in[2];
    const float* Wl1    = (const float*)d_in[3];
    const float* rel1   = (const float*)d_in[4];
    const float* W2     = (const float*)d_in[5];
    const float* Wl2    = (const float*)d_in[6];
    const float* rel2   = (const float*)d_in[7];
    const float* res    = (const float*)d_in[8];
    const float* jw     = (const float*)d_in[9];
    const float* ewj    = (const float*)d_in[10];
    const int*   eidx   = (const int*)d_in[11];
    const int*   etype  = (const int*)d_in[12];
    const int*   ejmp   = (const int*)d_in[13];

    const int ND = in_sizes[0];
    const int N  = ND / D;
    const int E  = in_sizes[12];
    const int EJ = in_sizes[10];
    const int RD = in_sizes[4];              // R*D elements per rel matrix
    const int R  = RD / D;                   // zero row index
    const int NP = ((N + 63) / 64) * 64;
    const int M  = 2 * N;

    float* out = (float*)d_out;          // change passthrough
    float* dch = out + (size_t)ND;       // dchange

    // workspace layout (16B-aligned chunks)
    char* w = (char*)d_ws;
    short* Abf1  = (short*)w;                  w += (size_t)NP * 256 * 2;
    short* Abf2  = (short*)w;                  w += (size_t)NP * 256 * 2;
    short* Bpk1  = (short*)w;                  w += (size_t)64 * 64 * 8 * 2;
    short* Bpk2  = (short*)w;                  w += (size_t)64 * 64 * 8 * 2;
    short* relb1 = (short*)w;                  w += (size_t)(RD + D) * 2;   // +zero row
    short* relb2 = (short*)w;                  w += (size_t)(RD + D) * 2;   // +zero row
    unsigned char* X81 = (unsigned char*)w;    w += (size_t)NP * 128;       // e5m2 emb
    unsigned char* X82 = (unsigned char*)w;    w += (size_t)NP * 128;       // e5m2 h1
    short* jh    = (short*)w;                  w += (size_t)NP * 128 * 2;   // f16 jump
    int* cnt     = (int*)w;                    w += (size_t)M * 4;
    int* offs    = (int*)w;                    w += (size_t)M * 4;
    int* bsum    = (int*)w;                    w += 256 * 4;
    int* slot    = (int*)w;                    w += (size_t)(E + EJ) * 4;
    int2* pairs  = (int2*)w;                   w += (size_t)(E + EJ) * 8;

    const int T = 256;
    const int NB2 = (M + 1023) / 1024;
    const int EB  = (E + EJ + T - 1) / T;

    hipMemsetAsync(cnt, 0, (size_t)M * sizeof(int), stream);

    // ---- concatenated CSR build (conv + jump), slot-recorded, no fill atomics ----
    hist_both<<<EB, T, 0, stream>>>(eidx + E, ejmp + EJ, cnt, slot, E, EJ, N);
    scan1<<<NB2, 256, 0, stream>>>(cnt, offs, bsum, M);
    scan2<<<1, 256, 0, stream>>>(bsum, NB2);
    scan3<<<(M + T - 1) / T, T, 0, stream>>>(offs, bsum, M);
    fill_both<<<EB, T, 0, stream>>>(eidx, eidx + E, etype, ejmp, ejmp + EJ, ewj,
                                    offs, slot, pairs, E, EJ, N);

    // ---- weight packs (f16) + rel -> f16 (+zero rows) ----
    pack_w<<<128, 64, 0, stream>>>(W1, Wl1, W2, Wl2, Bpk1, Bpk2);
    cvt_rel<<<(RD / 2 + 64 + T - 1) / T, T, 0, stream>>>(rel1, rel2, relb1, relb2, RD);

    // ---- emb -> f16 + e5m2 (NT in), change -> out (NT through) ----
    cvt_emb_copy<<<(N * 32 + T - 1) / T, T, 0, stream>>>(emb, change, Abf1, X81, out, N);

    int gatherB = (N + 3) / 4;
    int gemmB   = NP / 64;

    // ---- jump gather (emb-based) -> jh f16 ----
    gather_jump<<<gatherB, 256, 0, stream>>>(Abf1, jh, offs, cnt, pairs, N);

    // ---- layer 1: conv gather + GEMM (h1 -> Abf2 x-half f16 + X82 e5m2) ----
    gather_conv<<<gatherB, 256, 0, stream>>>(X81, relb1, Abf1, offs, cnt, pairs, N, R);
    mfma_gemm<<<gemmB, 256, 0, stream>>>(Abf1, Bpk1, res, Abf2, X82,
                                         nullptr, nullptr, nullptr, N);

    // ---- layer-2 conv gather ----
    gather_conv<<<gatherB, 256, 0, stream>>>(X82, relb2, Abf2, offs, cnt, pairs, N, R);

    // ---- layer 2 GEMM: dch = h1 + res*tanh(...) + jw*jh (NT out) ----
    mfma_gemm<<<gemmB, 256, 0, stream>>>(Abf2, Bpk2, res, nullptr, nullptr,
                                         jh, jw, dch, N);
}